// Round 1
// baseline (1067.589 us; speedup 1.0000x reference)
//
#include <hip/hip_runtime.h>
#include <math.h>

// Problem constants (fixed by the reference setup)
#define BATCH 8
#define NNODE 2048      // Nd == Ns
#define DIN   1024
#define DM    256
#define ROWS_TOTAL (BATCH * NNODE)   // 16384

// ---------------------------------------------------------------------------
// Kernel 1: P = l2norm(X @ W + b)    X:[R,1024] W:[1024,256] b:[256] P:[R,256]
// Block: 64 rows x 256 cols (full Dm), 256 threads, K-tile 16.
// Row L2 norm fused in-block (cols split across 16 tx lanes -> shuffle reduce).
// ---------------------------------------------------------------------------
__global__ __launch_bounds__(256) void cvgm_proj_norm(
    const float* __restrict__ X, const float* __restrict__ W,
    const float* __restrict__ bias, float* __restrict__ out)
{
    __shared__ float As[16][64];     // [kk][row]  (transposed A tile)
    __shared__ float Ws[16][256];    // [kk][col]

    const int tid = threadIdx.x;
    const int tx = tid & 15;         // col group: cols tx*4 + 64*jj + c
    const int ty = tid >> 4;         // row group: rows ty*4 + r
    const int row0 = blockIdx.x * 64;

    float acc[4][16];
    #pragma unroll
    for (int r = 0; r < 4; ++r)
        #pragma unroll
        for (int c = 0; c < 16; ++c) acc[r][c] = 0.f;

    const int arow = tid >> 2;          // 0..63
    const int ak   = (tid & 3) * 4;     // 0,4,8,12

    for (int k0 = 0; k0 < DIN; k0 += 16) {
        // global loads
        const float4 av = *(const float4*)(X + (size_t)(row0 + arow) * DIN + k0 + ak);
        float4 wv[4];
        int wk[4], wc[4];
        #pragma unroll
        for (int it = 0; it < 4; ++it) {
            const int lin = it * 1024 + tid * 4;
            wk[it] = lin >> 8;
            wc[it] = lin & 255;
            wv[it] = *(const float4*)(W + (size_t)(k0 + wk[it]) * DM + wc[it]);
        }
        __syncthreads();   // previous tile fully consumed
        As[ak + 0][arow] = av.x;
        As[ak + 1][arow] = av.y;
        As[ak + 2][arow] = av.z;
        As[ak + 3][arow] = av.w;
        #pragma unroll
        for (int it = 0; it < 4; ++it)
            *(float4*)(&Ws[wk[it]][wc[it]]) = wv[it];
        __syncthreads();

        #pragma unroll
        for (int kk = 0; kk < 16; ++kk) {
            const float4 a4 = *(const float4*)(&As[kk][ty * 4]);
            const float a[4] = {a4.x, a4.y, a4.z, a4.w};
            float wf[16];
            #pragma unroll
            for (int jj = 0; jj < 4; ++jj) {
                const float4 w4 = *(const float4*)(&Ws[kk][tx * 4 + jj * 64]);
                wf[jj * 4 + 0] = w4.x; wf[jj * 4 + 1] = w4.y;
                wf[jj * 4 + 2] = w4.z; wf[jj * 4 + 3] = w4.w;
            }
            #pragma unroll
            for (int r = 0; r < 4; ++r)
                #pragma unroll
                for (int c = 0; c < 16; ++c)
                    acc[r][c] += a[r] * wf[c];
        }
    }

    // bias
    float bf[16];
    #pragma unroll
    for (int jj = 0; jj < 4; ++jj) {
        const float4 b4 = *(const float4*)(bias + tx * 4 + jj * 64);
        bf[jj * 4 + 0] = b4.x; bf[jj * 4 + 1] = b4.y;
        bf[jj * 4 + 2] = b4.z; bf[jj * 4 + 3] = b4.w;
    }
    #pragma unroll
    for (int r = 0; r < 4; ++r)
        #pragma unroll
        for (int c = 0; c < 16; ++c) acc[r][c] += bf[c];

    // fused row L2 norm: 16 vals/thread + reduce across 16 tx lanes (same wave)
    #pragma unroll
    for (int r = 0; r < 4; ++r) {
        float ss = 0.f;
        #pragma unroll
        for (int c = 0; c < 16; ++c) ss += acc[r][c] * acc[r][c];
        ss += __shfl_xor(ss, 1);
        ss += __shfl_xor(ss, 2);
        ss += __shfl_xor(ss, 4);
        ss += __shfl_xor(ss, 8);
        const float inv = 1.0f / fmaxf(sqrtf(ss), 1e-12f);
        #pragma unroll
        for (int c = 0; c < 16; ++c) acc[r][c] *= inv;
    }

    float* orow = out + (size_t)(row0 + ty * 4) * DM;
    #pragma unroll
    for (int r = 0; r < 4; ++r)
        #pragma unroll
        for (int jj = 0; jj < 4; ++jj) {
            const float4 o = make_float4(acc[r][jj * 4 + 0], acc[r][jj * 4 + 1],
                                         acc[r][jj * 4 + 2], acc[r][jj * 4 + 3]);
            *(float4*)(orow + (size_t)r * DM + tx * 4 + jj * 64) = o;
        }
}

// ---------------------------------------------------------------------------
// Kernel 2: M0[b] = D[b] @ S[b]^T   D,S:[2048,256] -> C:[2048,2048]
// 128x128 block, 256 threads, 8x8 micro-tile (split rows/cols {base, base+64}
// so compute ds_read_b128 is conflict-free), K-tile 32.
// ---------------------------------------------------------------------------
__global__ __launch_bounds__(256) void cvgm_m0_gemm(
    const float* __restrict__ Dp, const float* __restrict__ Sp,
    float* __restrict__ C)
{
    __shared__ float Ds[32][128];   // [kk][row]
    __shared__ float Ss[32][128];   // [kk][col]

    const int tid = threadIdx.x;
    const int tx = tid & 15, ty = tid >> 4;
    const int bb = blockIdx.z;
    const int i0 = blockIdx.y * 128, j0 = blockIdx.x * 128;
    const float* Db = Dp + (size_t)bb * NNODE * DM;
    const float* Sb = Sp + (size_t)bb * NNODE * DM;

    float acc[8][8];
    #pragma unroll
    for (int ii = 0; ii < 8; ++ii)
        #pragma unroll
        for (int jj = 0; jj < 8; ++jj) acc[ii][jj] = 0.f;

    const int srow = tid >> 3;        // 0..31
    const int sk   = (tid & 7) * 4;   // 0..28

    for (int k0 = 0; k0 < DM; k0 += 32) {
        float4 dv[4], sv[4];
        #pragma unroll
        for (int it = 0; it < 4; ++it) {
            dv[it] = *(const float4*)(Db + (size_t)(i0 + it * 32 + srow) * DM + k0 + sk);
            sv[it] = *(const float4*)(Sb + (size_t)(j0 + it * 32 + srow) * DM + k0 + sk);
        }
        __syncthreads();
        #pragma unroll
        for (int it = 0; it < 4; ++it) {
            const int r = it * 32 + srow;
            Ds[sk + 0][r] = dv[it].x; Ds[sk + 1][r] = dv[it].y;
            Ds[sk + 2][r] = dv[it].z; Ds[sk + 3][r] = dv[it].w;
            Ss[sk + 0][r] = sv[it].x; Ss[sk + 1][r] = sv[it].y;
            Ss[sk + 2][r] = sv[it].z; Ss[sk + 3][r] = sv[it].w;
        }
        __syncthreads();
        #pragma unroll 8
        for (int kk = 0; kk < 32; ++kk) {
            const float4 a0 = *(const float4*)(&Ds[kk][ty * 4]);
            const float4 a1 = *(const float4*)(&Ds[kk][ty * 4 + 64]);
            const float4 b0 = *(const float4*)(&Ss[kk][tx * 4]);
            const float4 b1 = *(const float4*)(&Ss[kk][tx * 4 + 64]);
            const float ar[8] = {a0.x, a0.y, a0.z, a0.w, a1.x, a1.y, a1.z, a1.w};
            const float bc[8] = {b0.x, b0.y, b0.z, b0.w, b1.x, b1.y, b1.z, b1.w};
            #pragma unroll
            for (int ii = 0; ii < 8; ++ii)
                #pragma unroll
                for (int jj = 0; jj < 8; ++jj)
                    acc[ii][jj] += ar[ii] * bc[jj];
        }
    }

    float* Cb = C + (size_t)bb * NNODE * NNODE;
    #pragma unroll
    for (int ih = 0; ih < 2; ++ih)
        #pragma unroll
        for (int r = 0; r < 4; ++r) {
            const int i = i0 + ih * 64 + ty * 4 + r;
            const float4 o0 = make_float4(acc[ih * 4 + r][0], acc[ih * 4 + r][1],
                                          acc[ih * 4 + r][2], acc[ih * 4 + r][3]);
            const float4 o1 = make_float4(acc[ih * 4 + r][4], acc[ih * 4 + r][5],
                                          acc[ih * 4 + r][6], acc[ih * 4 + r][7]);
            *(float4*)(Cb + (size_t)i * NNODE + j0 + tx * 4) = o0;
            *(float4*)(Cb + (size_t)i * NNODE + j0 + 64 + tx * 4) = o1;
        }
}

// ---------------------------------------------------------------------------
// Kernel 3: u[b,i] = lse_j( M0[b,i,j] - v[b,j] )   one block per row
// ---------------------------------------------------------------------------
__global__ __launch_bounds__(256) void cvgm_row_lse(
    const float* __restrict__ M0, const float* __restrict__ v,
    float* __restrict__ u)
{
    const int row = blockIdx.x;              // b*2048 + i
    const int b = row >> 11;
    const float* Mr = M0 + (size_t)row * NNODE;
    const float* vb = v + (b << 11);
    const int tid = threadIdx.x;
    const int j0 = tid * 4;

    const float4 xa = *(const float4*)(Mr + j0);
    const float4 xb = *(const float4*)(Mr + j0 + 1024);
    const float4 va = *(const float4*)(vb + j0);
    const float4 vc = *(const float4*)(vb + j0 + 1024);
    float x[8] = {xa.x - va.x, xa.y - va.y, xa.z - va.z, xa.w - va.w,
                  xb.x - vc.x, xb.y - vc.y, xb.z - vc.z, xb.w - vc.w};
    float m = x[0];
    #pragma unroll
    for (int k = 1; k < 8; ++k) m = fmaxf(m, x[k]);
    float s = 0.f;
    #pragma unroll
    for (int k = 0; k < 8; ++k) s += expf(x[k] - m);

    #pragma unroll
    for (int off = 1; off < 64; off <<= 1) {
        const float m2 = __shfl_xor(m, off);
        const float s2 = __shfl_xor(s, off);
        const float mn = fmaxf(m, m2);
        s = s * expf(m - mn) + s2 * expf(m2 - mn);
        m = mn;
    }
    __shared__ float shm[4], shs[4];
    if ((tid & 63) == 0) { shm[tid >> 6] = m; shs[tid >> 6] = s; }
    __syncthreads();
    if (tid == 0) {
        m = shm[0]; s = shs[0];
        #pragma unroll
        for (int w = 1; w < 4; ++w) {
            const float m2 = shm[w], s2 = shs[w];
            const float mn = fmaxf(m, m2);
            s = s * expf(m - mn) + s2 * expf(m2 - mn);
            m = mn;
        }
        u[row] = m + logf(s);
    }
}

// ---------------------------------------------------------------------------
// Kernel 4: column-LSE partials.  grid (2 stripes, 16 row-chunks, 8 batches).
// Thread owns 4 adjacent columns, online LSE over 128 rows.
// ---------------------------------------------------------------------------
__global__ __launch_bounds__(256) void cvgm_col_lse_part(
    const float* __restrict__ M0, const float* __restrict__ u,
    float* __restrict__ pm, float* __restrict__ ps)
{
    const int b = blockIdx.z, chunk = blockIdx.y, stripe = blockIdx.x;
    const int j = stripe * 1024 + threadIdx.x * 4;
    const float* Mb = M0 + ((size_t)(b << 11) + chunk * 128) * NNODE;
    const float* ub = u + (b << 11) + chunk * 128;

    float m[4] = {-INFINITY, -INFINITY, -INFINITY, -INFINITY};
    float s[4] = {0.f, 0.f, 0.f, 0.f};
    for (int i = 0; i < 128; ++i) {
        const float ui = ub[i];
        const float4 val = *(const float4*)(Mb + (size_t)i * NNODE + j);
        const float x[4] = {val.x - ui, val.y - ui, val.z - ui, val.w - ui};
        #pragma unroll
        for (int c = 0; c < 4; ++c) {
            const float mn = fmaxf(m[c], x[c]);
            s[c] = s[c] * expf(m[c] - mn) + expf(x[c] - mn);
            m[c] = mn;
        }
    }
    const size_t base = ((size_t)b * 16 + chunk) * NNODE + j;
    *(float4*)(pm + base) = make_float4(m[0], m[1], m[2], m[3]);
    *(float4*)(ps + base) = make_float4(s[0], s[1], s[2], s[3]);
}

// ---------------------------------------------------------------------------
// Kernel 5: merge 16 column partials -> v[b,j]
// ---------------------------------------------------------------------------
__global__ __launch_bounds__(256) void cvgm_col_merge(
    const float* __restrict__ pm, const float* __restrict__ ps,
    float* __restrict__ v)
{
    const int idx = blockIdx.x * 256 + threadIdx.x;   // 0..16383
    const int b = idx >> 11, j = idx & 2047;
    float m = -INFINITY, s = 0.f;
    #pragma unroll
    for (int c = 0; c < 16; ++c) {
        const size_t base = ((size_t)b * 16 + c) * NNODE + j;
        const float m2 = pm[base], s2 = ps[base];
        const float mn = fmaxf(m, m2);
        s = s * expf(m - mn) + s2 * expf(m2 - mn);
        m = mn;
    }
    v[idx] = m + logf(s);
}

// ---------------------------------------------------------------------------
// Kernel 6: assignment = exp(M0 - u - v) in place; per-row partial of
// sum(assignment * M0).  One block per row.
// ---------------------------------------------------------------------------
__global__ __launch_bounds__(256) void cvgm_final(
    float* __restrict__ M, const float* __restrict__ u,
    const float* __restrict__ v, float* __restrict__ spart)
{
    const int row = blockIdx.x;
    const int b = row >> 11;
    float* Mr = M + (size_t)row * NNODE;
    const float* vb = v + (b << 11);
    const float ui = u[row];
    const int j0 = threadIdx.x * 4;

    float acc = 0.f;
    #pragma unroll
    for (int h = 0; h < 2; ++h) {
        const float4 mm = *(const float4*)(Mr + j0 + h * 1024);
        const float4 vv = *(const float4*)(vb + j0 + h * 1024);
        float4 a;
        a.x = expf(mm.x - ui - vv.x);
        a.y = expf(mm.y - ui - vv.y);
        a.z = expf(mm.z - ui - vv.z);
        a.w = expf(mm.w - ui - vv.w);
        acc += a.x * mm.x + a.y * mm.y + a.z * mm.z + a.w * mm.w;
        *(float4*)(Mr + j0 + h * 1024) = a;
    }
    #pragma unroll
    for (int off = 1; off < 64; off <<= 1) acc += __shfl_xor(acc, off);
    __shared__ float sh[4];
    if ((threadIdx.x & 63) == 0) sh[threadIdx.x >> 6] = acc;
    __syncthreads();
    if (threadIdx.x == 0) spart[row] = sh[0] + sh[1] + sh[2] + sh[3];
}

// ---------------------------------------------------------------------------
// Kernel 7: match_score[b] = sum(spart[b,:]) / 2048
// ---------------------------------------------------------------------------
__global__ __launch_bounds__(256) void cvgm_score(
    const float* __restrict__ spart, float* __restrict__ score)
{
    const int b = blockIdx.x;
    float acc = 0.f;
    for (int t = threadIdx.x; t < NNODE; t += 256) acc += spart[(b << 11) + t];
    #pragma unroll
    for (int off = 1; off < 64; off <<= 1) acc += __shfl_xor(acc, off);
    __shared__ float sh[4];
    if ((threadIdx.x & 63) == 0) sh[threadIdx.x >> 6] = acc;
    __syncthreads();
    if (threadIdx.x == 0) score[b] = (sh[0] + sh[1] + sh[2] + sh[3]) * (1.0f / 2048.0f);
}

// ---------------------------------------------------------------------------
extern "C" void kernel_launch(void* const* d_in, const int* in_sizes, int n_in,
                              void* d_out, int out_size, void* d_ws, size_t ws_size,
                              hipStream_t stream) {
    (void)in_sizes; (void)n_in; (void)out_size; (void)ws_size;
    const float* drone = (const float*)d_in[0];   // [8,2048,1024]
    const float* sat   = (const float*)d_in[1];   // [8,2048,1024]
    const float* W     = (const float*)d_in[2];   // [1024,256]
    const float* bias  = (const float*)d_in[3];   // [256]

    float* out   = (float*)d_out;
    float* M0    = out;                                    // [8,2048,2048] (becomes assignment)
    float* score = out + (size_t)BATCH * NNODE * NNODE;    // [8]

    // workspace layout (floats)
    float* dproj = (float*)d_ws;                           // 8*2048*256
    float* sproj = dproj + (size_t)BATCH * NNODE * DM;     // 8*2048*256
    float* u     = sproj + (size_t)BATCH * NNODE * DM;     // 16384
    float* v     = u + ROWS_TOTAL;                         // 16384
    float* pm    = v + ROWS_TOTAL;                         // 8*16*2048
    float* ps    = pm + (size_t)BATCH * 16 * NNODE;        // 8*16*2048
    float* spart = ps + (size_t)BATCH * 16 * NNODE;        // 16384

    hipMemsetAsync(v, 0, ROWS_TOTAL * sizeof(float), stream);

    cvgm_proj_norm<<<ROWS_TOTAL / 64, 256, 0, stream>>>(drone, W, bias, dproj);
    cvgm_proj_norm<<<ROWS_TOTAL / 64, 256, 0, stream>>>(sat, W, bias, sproj);
    cvgm_m0_gemm<<<dim3(16, 16, 8), 256, 0, stream>>>(dproj, sproj, M0);

    for (int it = 0; it < 5; ++it) {
        cvgm_row_lse<<<ROWS_TOTAL, 256, 0, stream>>>(M0, v, u);
        cvgm_col_lse_part<<<dim3(2, 16, 8), 256, 0, stream>>>(M0, u, pm, ps);
        cvgm_col_merge<<<ROWS_TOTAL / 256, 256, 0, stream>>>(pm, ps, v);
    }

    cvgm_final<<<ROWS_TOTAL, 256, 0, stream>>>(M0, u, v, spart);
    cvgm_score<<<BATCH, 256, 0, stream>>>(spart, score);
}

// Round 2
// 283.107 us; speedup vs baseline: 3.7710x; 3.7710x over previous
//
#include <hip/hip_runtime.h>
#include <math.h>

#define BATCH 8
#define NNODE 2048
#define DIN   1024
#define DM    256
#define ROWS_TOTAL (BATCH * NNODE)   // 16384

typedef unsigned short u16;
typedef __attribute__((ext_vector_type(8))) short short8;   // 8 bf16 (4 VGPR)
typedef __attribute__((ext_vector_type(4))) float f32x4;

__device__ __forceinline__ u16 f2b(float f) {   // fp32 -> bf16 RNE
    union { float f; unsigned u; } v; v.f = f;
    unsigned r = v.u + 0x7fffu + ((v.u >> 16) & 1u);
    return (u16)(r >> 16);
}
__device__ __forceinline__ float b2f(u16 h) {
    union { unsigned u; float f; } v; v.u = ((unsigned)h) << 16; return v.f;
}

// load 8 contiguous elements as f32, templated on storage type
template <typename MT> struct Ld8;
template <> struct Ld8<u16> {
    static __device__ __forceinline__ void go(const u16* p, float* x) {
        short8 r = *(const short8*)p;
        #pragma unroll
        for (int j = 0; j < 8; ++j) x[j] = b2f((u16)r[j]);
    }
};
template <> struct Ld8<float> {
    static __device__ __forceinline__ void go(const float* p, float* x) {
        float4 a = *(const float4*)p, b = *(const float4*)(p + 4);
        x[0]=a.x; x[1]=a.y; x[2]=a.z; x[3]=a.w;
        x[4]=b.x; x[5]=b.y; x[6]=b.z; x[7]=b.w;
    }
};

// ---------------------------------------------------------------------------
// Kernel 0: Wt[c][k] = bf16(W[k][c])   (1024x256 f32 -> 256x1024 bf16)
// ---------------------------------------------------------------------------
__global__ __launch_bounds__(256) void cvgm_prep_w(
    const float* __restrict__ W, u16* __restrict__ Wt)
{
    __shared__ float t[32][33];
    const int tx = threadIdx.x & 31, ty = threadIdx.x >> 5;   // 32 x 8
    const int k0 = blockIdx.x * 32, c0 = blockIdx.y * 32;
    #pragma unroll
    for (int r = 0; r < 4; ++r) {
        const int kl = ty * 4 + r;
        t[kl][tx] = W[(size_t)(k0 + kl) * DM + c0 + tx];
    }
    __syncthreads();
    #pragma unroll
    for (int r = 0; r < 4; ++r) {
        const int cl = ty * 4 + r;
        Wt[(size_t)(c0 + cl) * DIN + k0 + tx] = f2b(t[tx][cl]);
    }
}

// ---------------------------------------------------------------------------
// Kernel 1: P = bf16( l2norm(X @ W + b) )    MFMA bf16, block = 32 rows x 256
// cols, 4 waves (wave w owns cols w*64), BK=64, K=1024.  XOR chunk swizzle.
// ---------------------------------------------------------------------------
__global__ __launch_bounds__(256) void cvgm_proj_mfma(
    const float* __restrict__ X, const u16* __restrict__ Wt,
    const float* __restrict__ bias, u16* __restrict__ P)
{
    __shared__ u16 As[32 * 64];     // 4 KB  [row][k] chunk-swizzled
    __shared__ u16 Bs[256 * 64];    // 32 KB [col][k] chunk-swizzled
    __shared__ float rsum[4][32];

    const int tid = threadIdx.x;
    const int lane = tid & 63, wid = tid >> 6;
    const int l15 = lane & 15, l4 = lane >> 4;
    const int row0 = blockIdx.x * 32;

    f32x4 acc[2][4];
    #pragma unroll
    for (int m = 0; m < 2; ++m)
        #pragma unroll
        for (int n = 0; n < 4; ++n) acc[m][n] = (f32x4){0.f, 0.f, 0.f, 0.f};

    const int arow = tid >> 3, ac = tid & 7;   // A: 1 chunk/thread

    for (int k0 = 0; k0 < DIN; k0 += 64) {
        const float* src = X + (size_t)(row0 + arow) * DIN + k0 + ac * 8;
        const float4 x0 = *(const float4*)src;
        const float4 x1 = *(const float4*)(src + 4);
        short8 wb[8];
        #pragma unroll
        for (int it = 0; it < 8; ++it) {
            const int id = it * 256 + tid;
            const int col = id >> 3, cc = id & 7;
            wb[it] = *(const short8*)(Wt + (size_t)col * DIN + k0 + cc * 8);
        }
        __syncthreads();
        short8 ap;
        ap[0]=(short)f2b(x0.x); ap[1]=(short)f2b(x0.y); ap[2]=(short)f2b(x0.z); ap[3]=(short)f2b(x0.w);
        ap[4]=(short)f2b(x1.x); ap[5]=(short)f2b(x1.y); ap[6]=(short)f2b(x1.z); ap[7]=(short)f2b(x1.w);
        *(short8*)(As + (arow * 8 + (ac ^ (arow & 7))) * 8) = ap;
        #pragma unroll
        for (int it = 0; it < 8; ++it) {
            const int id = it * 256 + tid;
            const int col = id >> 3, cc = id & 7;
            *(short8*)(Bs + (col * 8 + (cc ^ (col & 7))) * 8) = wb[it];
        }
        __syncthreads();
        #pragma unroll
        for (int ks = 0; ks < 2; ++ks) {
            const int ch = ks * 4 + l4;
            short8 af[2], bfr[4];
            #pragma unroll
            for (int m = 0; m < 2; ++m) {
                const int row = m * 16 + l15;
                af[m] = *(const short8*)(As + (row * 8 + (ch ^ (row & 7))) * 8);
            }
            #pragma unroll
            for (int n = 0; n < 4; ++n) {
                const int col = wid * 64 + n * 16 + l15;
                bfr[n] = *(const short8*)(Bs + (col * 8 + (ch ^ (col & 7))) * 8);
            }
            #pragma unroll
            for (int m = 0; m < 2; ++m)
                #pragma unroll
                for (int n = 0; n < 4; ++n)
                    acc[m][n] = __builtin_amdgcn_mfma_f32_16x16x32_bf16(af[m], bfr[n], acc[m][n], 0, 0, 0);
        }
        __syncthreads();
    }

    // bias
    #pragma unroll
    for (int n = 0; n < 4; ++n) {
        const float bv = bias[wid * 64 + n * 16 + l15];
        #pragma unroll
        for (int m = 0; m < 2; ++m)
            #pragma unroll
            for (int r = 0; r < 4; ++r) acc[m][n][r] += bv;
    }
    // row sum-of-squares: lane covers 4 cols (n), reduce across 16 l15 lanes
    float ss[2][4];
    #pragma unroll
    for (int m = 0; m < 2; ++m)
        #pragma unroll
        for (int r = 0; r < 4; ++r) {
            float s = 0.f;
            #pragma unroll
            for (int n = 0; n < 4; ++n) s += acc[m][n][r] * acc[m][n][r];
            s += __shfl_xor(s, 1); s += __shfl_xor(s, 2);
            s += __shfl_xor(s, 4); s += __shfl_xor(s, 8);
            ss[m][r] = s;
        }
    if (l15 == 0) {
        #pragma unroll
        for (int m = 0; m < 2; ++m)
            #pragma unroll
            for (int r = 0; r < 4; ++r) rsum[wid][m * 16 + l4 * 4 + r] = ss[m][r];
    }
    __syncthreads();
    #pragma unroll
    for (int m = 0; m < 2; ++m)
        #pragma unroll
        for (int r = 0; r < 4; ++r) {
            const int row = m * 16 + l4 * 4 + r;
            const float tot = rsum[0][row] + rsum[1][row] + rsum[2][row] + rsum[3][row];
            const float inv = 1.0f / fmaxf(sqrtf(tot), 1e-12f);
            #pragma unroll
            for (int n = 0; n < 4; ++n) {
                const int col = wid * 64 + n * 16 + l15;
                P[(size_t)(row0 + row) * DM + col] = f2b(acc[m][n][r] * inv);
            }
        }
}

// ---------------------------------------------------------------------------
// Kernel 2: M0[b] = D[b] @ S[b]^T   bf16 MFMA, 128x128 tile, 4 waves (2x2 of
// 64x64), BK=64, K=256.  Both operands row-major [node][k] -> same frag path.
// ---------------------------------------------------------------------------
template <typename OT>
__global__ __launch_bounds__(256) void cvgm_m0_mfma(
    const u16* __restrict__ Dp, const u16* __restrict__ Sp, OT* __restrict__ C)
{
    __shared__ u16 As[128 * 64];   // 16 KB
    __shared__ u16 Bs[128 * 64];   // 16 KB

    const int tid = threadIdx.x;
    const int lane = tid & 63, wid = tid >> 6;
    const int wr = wid >> 1, wc = wid & 1;
    const int l15 = lane & 15, l4 = lane >> 4;
    const int bb = blockIdx.z;
    const int i0 = blockIdx.y * 128, j0 = blockIdx.x * 128;
    const u16* Db = Dp + (size_t)bb * NNODE * DM;
    const u16* Sb = Sp + (size_t)bb * NNODE * DM;

    f32x4 acc[4][4];
    #pragma unroll
    for (int m = 0; m < 4; ++m)
        #pragma unroll
        for (int n = 0; n < 4; ++n) acc[m][n] = (f32x4){0.f, 0.f, 0.f, 0.f};

    for (int k0 = 0; k0 < DM; k0 += 64) {
        short8 ra[4], rb[4];
        #pragma unroll
        for (int it = 0; it < 4; ++it) {
            const int id = it * 256 + tid;          // 0..1023
            const int row = id >> 3, c = id & 7;
            ra[it] = *(const short8*)(Db + (size_t)(i0 + row) * DM + k0 + c * 8);
            rb[it] = *(const short8*)(Sb + (size_t)(j0 + row) * DM + k0 + c * 8);
        }
        __syncthreads();
        #pragma unroll
        for (int it = 0; it < 4; ++it) {
            const int id = it * 256 + tid;
            const int row = id >> 3, c = id & 7;
            const int sl = row * 8 + (c ^ (row & 7));
            *(short8*)(As + sl * 8) = ra[it];
            *(short8*)(Bs + sl * 8) = rb[it];
        }
        __syncthreads();
        #pragma unroll
        for (int ks = 0; ks < 2; ++ks) {
            const int ch = ks * 4 + l4;
            short8 af[4], bfr[4];
            #pragma unroll
            for (int m = 0; m < 4; ++m) {
                const int row = wr * 64 + m * 16 + l15;
                af[m] = *(const short8*)(As + (row * 8 + (ch ^ (row & 7))) * 8);
            }
            #pragma unroll
            for (int n = 0; n < 4; ++n) {
                const int col = wc * 64 + n * 16 + l15;
                bfr[n] = *(const short8*)(Bs + (col * 8 + (ch ^ (col & 7))) * 8);
            }
            #pragma unroll
            for (int m = 0; m < 4; ++m)
                #pragma unroll
                for (int n = 0; n < 4; ++n)
                    acc[m][n] = __builtin_amdgcn_mfma_f32_16x16x32_bf16(af[m], bfr[n], acc[m][n], 0, 0, 0);
        }
        __syncthreads();
    }

    OT* Cb = C + (size_t)bb * NNODE * NNODE;
    #pragma unroll
    for (int m = 0; m < 4; ++m) {
        const int row = i0 + wr * 64 + m * 16 + l4 * 4;
        #pragma unroll
        for (int n = 0; n < 4; ++n) {
            const int col = j0 + wc * 64 + n * 16 + l15;
            #pragma unroll
            for (int r = 0; r < 4; ++r) {
                const float val = acc[m][n][r];
                if constexpr (sizeof(OT) == 2)
                    Cb[(size_t)(row + r) * NNODE + col] = (OT)f2b(val);
                else
                    Cb[(size_t)(row + r) * NNODE + col] = (OT)val;
            }
        }
    }
}

// ---------------------------------------------------------------------------
// Kernel 3: u[b,i] = log( sum_j exp(M0[b,i,j] - v[b,j]) )   (args bounded, no
// max tracking needed).  One block per row.
// ---------------------------------------------------------------------------
template <typename MT>
__global__ __launch_bounds__(256) void cvgm_row_lse(
    const MT* __restrict__ M0, const float* __restrict__ v, float* __restrict__ u)
{
    const int row = blockIdx.x;
    const int b = row >> 11;
    const MT* Mr = M0 + (size_t)row * NNODE;
    const float* vb = v + (b << 11);
    const int j0 = threadIdx.x * 8;

    float x[8];
    Ld8<MT>::go(Mr + j0, x);
    const float4 va = *(const float4*)(vb + j0);
    const float4 vc = *(const float4*)(vb + j0 + 4);
    const float vv[8] = {va.x, va.y, va.z, va.w, vc.x, vc.y, vc.z, vc.w};
    float s = 0.f;
    #pragma unroll
    for (int k = 0; k < 8; ++k) s += __expf(x[k] - vv[k]);
    #pragma unroll
    for (int off = 1; off < 64; off <<= 1) s += __shfl_xor(s, off);
    __shared__ float sh[4];
    if ((threadIdx.x & 63) == 0) sh[threadIdx.x >> 6] = s;
    __syncthreads();
    if (threadIdx.x == 0) u[row] = __logf(sh[0] + sh[1] + sh[2] + sh[3]);
}

// ---------------------------------------------------------------------------
// Kernel 4: column partial sums of exp(M0 - u).  64 chunks x 32 rows, thread
// owns 8 adjacent columns.
// ---------------------------------------------------------------------------
template <typename MT>
__global__ __launch_bounds__(256) void cvgm_col_part(
    const MT* __restrict__ M0, const float* __restrict__ u, float* __restrict__ ps)
{
    const int chunk = blockIdx.x;    // 0..63
    const int b = blockIdx.y;
    const int j0 = threadIdx.x * 8;
    const MT* Mb = M0 + ((size_t)(b << 11) + chunk * 32) * NNODE;
    const float* ub = u + (b << 11) + chunk * 32;

    float s[8] = {0.f, 0.f, 0.f, 0.f, 0.f, 0.f, 0.f, 0.f};
    for (int i = 0; i < 32; ++i) {
        const float ui = ub[i];
        float x[8];
        Ld8<MT>::go(Mb + (size_t)i * NNODE + j0, x);
        #pragma unroll
        for (int c = 0; c < 8; ++c) s[c] += __expf(x[c] - ui);
    }
    float* dst = ps + (size_t)(b * 64 + chunk) * NNODE + j0;
    *(float4*)(dst)     = make_float4(s[0], s[1], s[2], s[3]);
    *(float4*)(dst + 4) = make_float4(s[4], s[5], s[6], s[7]);
}

// ---------------------------------------------------------------------------
// Kernel 5: v[b,j] = log( sum over 64 chunk partials )
// ---------------------------------------------------------------------------
__global__ __launch_bounds__(256) void cvgm_col_merge(
    const float* __restrict__ ps, float* __restrict__ v)
{
    const int idx = blockIdx.x * 256 + threadIdx.x;   // 0..16383
    const int b = idx >> 11, j = idx & 2047;
    float s = 0.f;
    #pragma unroll 8
    for (int c = 0; c < 64; ++c) s += ps[(size_t)(b * 64 + c) * NNODE + j];
    v[idx] = __logf(s);
}

// ---------------------------------------------------------------------------
// Kernel 6: assignment = exp(M0 - u - v) -> out (f32); per-row partial of
// sum(assignment * M0).  NOTE: no __restrict__ on M0/out (may alias).
// ---------------------------------------------------------------------------
template <typename MT>
__global__ __launch_bounds__(256) void cvgm_final(
    const MT* M0, const float* __restrict__ u, const float* __restrict__ v,
    float* out, float* __restrict__ spart)
{
    const int row = blockIdx.x;
    const int b = row >> 11;
    const MT* Mr = M0 + (size_t)row * NNODE;
    float* Or = out + (size_t)row * NNODE;
    const float* vb = v + (b << 11);
    const float ui = u[row];
    const int j0 = threadIdx.x * 8;

    float x[8];
    Ld8<MT>::go(Mr + j0, x);
    const float4 va = *(const float4*)(vb + j0);
    const float4 vc = *(const float4*)(vb + j0 + 4);
    const float vv[8] = {va.x, va.y, va.z, va.w, vc.x, vc.y, vc.z, vc.w};
    float a[8], accv = 0.f;
    #pragma unroll
    for (int k = 0; k < 8; ++k) {
        a[k] = __expf(x[k] - ui - vv[k]);
        accv += a[k] * x[k];
    }
    *(float4*)(Or + j0)     = make_float4(a[0], a[1], a[2], a[3]);
    *(float4*)(Or + j0 + 4) = make_float4(a[4], a[5], a[6], a[7]);

    #pragma unroll
    for (int off = 1; off < 64; off <<= 1) accv += __shfl_xor(accv, off);
    __shared__ float sh[4];
    if ((threadIdx.x & 63) == 0) sh[threadIdx.x >> 6] = accv;
    __syncthreads();
    if (threadIdx.x == 0) spart[row] = sh[0] + sh[1] + sh[2] + sh[3];
}

// ---------------------------------------------------------------------------
// Kernel 7: match_score[b] = sum(spart[b,:]) / 2048
// ---------------------------------------------------------------------------
__global__ __launch_bounds__(256) void cvgm_score(
    const float* __restrict__ spart, float* __restrict__ score)
{
    const int b = blockIdx.x;
    float acc = 0.f;
    for (int t = threadIdx.x; t < NNODE; t += 256) acc += spart[(b << 11) + t];
    #pragma unroll
    for (int off = 1; off < 64; off <<= 1) acc += __shfl_xor(acc, off);
    __shared__ float sh[4];
    if ((threadIdx.x & 63) == 0) sh[threadIdx.x >> 6] = acc;
    __syncthreads();
    if (threadIdx.x == 0) score[b] = (sh[0] + sh[1] + sh[2] + sh[3]) * (1.0f / 2048.0f);
}

// ---------------------------------------------------------------------------
extern "C" void kernel_launch(void* const* d_in, const int* in_sizes, int n_in,
                              void* d_out, int out_size, void* d_ws, size_t ws_size,
                              hipStream_t stream) {
    (void)in_sizes; (void)n_in; (void)out_size;
    const float* drone = (const float*)d_in[0];
    const float* sat   = (const float*)d_in[1];
    const float* W     = (const float*)d_in[2];
    const float* bias  = (const float*)d_in[3];

    float* out   = (float*)d_out;
    float* score = out + (size_t)BATCH * NNODE * NNODE;

    char* ws = (char*)d_ws;
    const size_t SZ_M0B  = (size_t)BATCH * NNODE * NNODE * 2;   // 67108864
    const size_t SZ_PROJ = (size_t)ROWS_TOTAL * DM * 2;         // 8388608
    const size_t SZ_WT   = (size_t)DM * DIN * 2;                // 524288
    const size_t SZ_UV   = (size_t)ROWS_TOTAL * 4;              // 65536
    const size_t SZ_PS   = (size_t)BATCH * 64 * NNODE * 4;      // 4194304
    const size_t NEED_BIG = SZ_M0B + 2 * SZ_PROJ + SZ_WT + 3 * SZ_UV + SZ_PS;

    const bool big = ws_size >= NEED_BIG;

    if (big) {
        u16* M0b   = (u16*)ws;
        u16* dproj = (u16*)(ws + SZ_M0B);
        u16* sproj = dproj + (size_t)ROWS_TOTAL * DM;
        u16* Wt    = sproj + (size_t)ROWS_TOTAL * DM;
        float* u   = (float*)(ws + SZ_M0B + 2 * SZ_PROJ + SZ_WT);
        float* v   = u + ROWS_TOTAL;
        float* ps  = v + ROWS_TOTAL;
        float* spart = ps + (size_t)BATCH * 64 * NNODE;

        hipMemsetAsync(v, 0, SZ_UV, stream);
        cvgm_prep_w<<<dim3(32, 8), 256, 0, stream>>>(W, Wt);
        cvgm_proj_mfma<<<ROWS_TOTAL / 32, 256, 0, stream>>>(drone, Wt, bias, dproj);
        cvgm_proj_mfma<<<ROWS_TOTAL / 32, 256, 0, stream>>>(sat, Wt, bias, sproj);
        cvgm_m0_mfma<u16><<<dim3(16, 16, 8), 256, 0, stream>>>(dproj, sproj, M0b);
        for (int it = 0; it < 5; ++it) {
            cvgm_row_lse<u16><<<ROWS_TOTAL, 256, 0, stream>>>(M0b, v, u);
            cvgm_col_part<u16><<<dim3(64, 8), 256, 0, stream>>>(M0b, u, ps);
            cvgm_col_merge<<<ROWS_TOTAL / 256, 256, 0, stream>>>(ps, v);
        }
        cvgm_final<u16><<<ROWS_TOTAL, 256, 0, stream>>>(M0b, u, v, out, spart);
        cvgm_score<<<BATCH, 256, 0, stream>>>(spart, score);
    } else {
        // fallback: M0 fp32 lives in d_out, transformed in place at the end
        float* M0  = out;
        u16* dproj = (u16*)ws;
        u16* sproj = dproj + (size_t)ROWS_TOTAL * DM;
        u16* Wt    = sproj + (size_t)ROWS_TOTAL * DM;
        float* u   = (float*)(ws + 2 * SZ_PROJ + SZ_WT);
        float* v   = u + ROWS_TOTAL;
        float* ps  = v + ROWS_TOTAL;
        float* spart = ps + (size_t)BATCH * 64 * NNODE;

        hipMemsetAsync(v, 0, SZ_UV, stream);
        cvgm_prep_w<<<dim3(32, 8), 256, 0, stream>>>(W, Wt);
        cvgm_proj_mfma<<<ROWS_TOTAL / 32, 256, 0, stream>>>(drone, Wt, bias, dproj);
        cvgm_proj_mfma<<<ROWS_TOTAL / 32, 256, 0, stream>>>(sat, Wt, bias, sproj);
        cvgm_m0_mfma<float><<<dim3(16, 16, 8), 256, 0, stream>>>(dproj, sproj, M0);
        for (int it = 0; it < 5; ++it) {
            cvgm_row_lse<float><<<ROWS_TOTAL, 256, 0, stream>>>(M0, v, u);
            cvgm_col_part<float><<<dim3(64, 8), 256, 0, stream>>>(M0, u, ps);
            cvgm_col_merge<<<ROWS_TOTAL / 256, 256, 0, stream>>>(ps, v);
        }
        cvgm_final<float><<<ROWS_TOTAL, 256, 0, stream>>>(M0, u, v, out, spart);
        cvgm_score<<<BATCH, 256, 0, stream>>>(spart, score);
    }
}